// Round 10
// baseline (2243.096 us; speedup 1.0000x reference)
//
#include <hip/hip_runtime.h>
#include <stdint.h>

#define NPTS 8192
#define NBATCH 8
#define NPOINT 2048
#define KNN_K 16
#define CIN 64
#define COUT 128

typedef unsigned long long u64;
typedef unsigned int u32;

#define MAXU64(a, b) (((a) > (b)) ? (a) : (b))
#define MAXF64(a, b) fmax((a), (b))

// wave64 max-reduce of a positive-finite f64 key via DPP row_shr + row_bcast.
// Result valid in lane 63. Proven rounds 4-9.
__device__ __forceinline__ double wave_max_f64(double v) {
#define DPPSTEP(C)                                                             \
  {                                                                            \
    u64 k = (u64)__double_as_longlong(v);                                      \
    u32 lo = (u32)k, hi = (u32)(k >> 32);                                      \
    u32 nlo = (u32)__builtin_amdgcn_update_dpp(0, (int)lo, C, 0xf, 0xf, true); \
    u32 nhi = (u32)__builtin_amdgcn_update_dpp(0, (int)hi, C, 0xf, 0xf, true); \
    double o = __longlong_as_double((long long)(((u64)nhi << 32) | nlo));      \
    v = fmax(v, o);                                                            \
  }
  DPPSTEP(0x111)
  DPPSTEP(0x112)
  DPPSTEP(0x114)
  DPPSTEP(0x118)
  DPPSTEP(0x142)
  DPPSTEP(0x143)
#undef DPPSTEP
  return v;
}

// 16-lane row max of positive-finite f64; lane 15 of each row holds the max.
__device__ __forceinline__ double row16_max_f64(double v) {
#define DPPSTEP(C)                                                             \
  {                                                                            \
    u64 k = (u64)__double_as_longlong(v);                                      \
    u32 lo = (u32)k, hi = (u32)(k >> 32);                                      \
    u32 nlo = (u32)__builtin_amdgcn_update_dpp(0, (int)lo, C, 0xf, 0xf, true); \
    u32 nhi = (u32)__builtin_amdgcn_update_dpp(0, (int)hi, C, 0xf, 0xf, true); \
    double o = __longlong_as_double((long long)(((u64)nhi << 32) | nlo));      \
    v = fmax(v, o);                                                            \
  }
  DPPSTEP(0x111)
  DPPSTEP(0x112)
  DPPSTEP(0x114)
  DPPSTEP(0x118)
#undef DPPSTEP
  return v;
}

// wave64 max-reduce on exact u64 keys (for knn).
__device__ __forceinline__ u64 wave_max_u64(u64 k) {
  u32 lo = (u32)k, hi = (u32)(k >> 32);
#define DPPSTEP(C)                                                             \
  {                                                                            \
    u32 nlo = (u32)__builtin_amdgcn_update_dpp(0, (int)lo, C, 0xf, 0xf, true); \
    u32 nhi = (u32)__builtin_amdgcn_update_dpp(0, (int)hi, C, 0xf, 0xf, true); \
    u64 cur = ((u64)hi << 32) | lo;                                            \
    u64 oth = ((u64)nhi << 32) | nlo;                                          \
    if (oth > cur) { hi = nhi; lo = nlo; }                                     \
  }
  DPPSTEP(0x111)
  DPPSTEP(0x112)
  DPPSTEP(0x114)
  DPPSTEP(0x118)
  DPPSTEP(0x142)
  DPPSTEP(0x143)
#undef DPPSTEP
  return ((u64)hi << 32) | lo;
}

// wave64 min/max f32, invalid lanes keep own value (bound_ctrl=false).
__device__ __forceinline__ float wave_min_f32(float v) {
#define STEP(C)                                                                \
  {                                                                            \
    int o = __builtin_amdgcn_update_dpp((int)__float_as_uint(v),               \
                                        (int)__float_as_uint(v), C, 0xf, 0xf,  \
                                        false);                                \
    v = fminf(v, __uint_as_float((u32)o));                                     \
  }
  STEP(0x111) STEP(0x112) STEP(0x114) STEP(0x118) STEP(0x142) STEP(0x143)
#undef STEP
  return v;
}
__device__ __forceinline__ float wave_max_f32(float v) {
#define STEP(C)                                                                \
  {                                                                            \
    int o = __builtin_amdgcn_update_dpp((int)__float_as_uint(v),               \
                                        (int)__float_as_uint(v), C, 0xf, 0xf,  \
                                        false);                                \
    v = fmaxf(v, __uint_as_float((u32)o));                                     \
  }
  STEP(0x111) STEP(0x112) STEP(0x114) STEP(0x118) STEP(0x142) STEP(0x143)
#undef STEP
  return v;
}

__device__ __forceinline__ float bcast63(float v) {
  return __uint_as_float(
      (u32)__builtin_amdgcn_readlane((int)__float_as_uint(v), 63));
}

__device__ __forceinline__ u32 sp2(u32 v) {  // 2 bits -> bits 0,3
  return (v & 1u) | ((v & 2u) << 2);
}

// ---------------- Kernel 1: FPS with exact 2-at-a-time speculation ----------
// grid NBATCH, block 512 (8 waves). Morton sort + register slices + bit-exact
// bbox skip as r9. NEW: each round posts the wave's exact top-2 keys; the
// block resolves the global top-2 (m1,m2). cent[it]=m1. If m2's key provably
// survives the m1-update (bitwise fminf test), cent[it+1]=m2 and the next
// round applies BOTH centroids fused (identical to two sequential reference
// rounds) -> ~2 centroids per barrier round.
// Key = (dist_bits<<32)|((8191-orig)<<13)|pos : argmax, first-orig tie-break.
__global__ __launch_bounds__(512) void fps_kernel(const float* __restrict__ xyz,
                                                  int* __restrict__ cent) {
  const int b = blockIdx.x;
  const int tid = threadIdx.x;
  const int lane = tid & 63;
  const int wid = tid >> 6;  // 0..7
  const float* xb = xyz + (size_t)b * NPTS * 3;

  __shared__ __align__(16) float4 XYZ4[NPTS];  // 128 KB
  __shared__ float gred[8][6];
  __shared__ int cnt64[64], base64[64], cur64[64];
  __shared__ __align__(16) u64 kbuf[2][16];    // [w]=m1w, [8+w]=m2w

  // ---- load 16 pts/thread + global bbox ----
  float lx[16], ly[16], lz[16];
  float xl = 3e38f, xh = -3e38f, yl = 3e38f, yh = -3e38f, zl = 3e38f, zh = -3e38f;
#pragma unroll
  for (int j = 0; j < 16; ++j) {
    int i = tid + 512 * j;
    float x = xb[i * 3 + 0], y = xb[i * 3 + 1], z = xb[i * 3 + 2];
    lx[j] = x; ly[j] = y; lz[j] = z;
    xl = fminf(xl, x); xh = fmaxf(xh, x);
    yl = fminf(yl, y); yh = fmaxf(yh, y);
    zl = fminf(zl, z); zh = fmaxf(zh, z);
  }
  xl = wave_min_f32(xl); xh = wave_max_f32(xh);
  yl = wave_min_f32(yl); yh = wave_max_f32(yh);
  zl = wave_min_f32(zl); zh = wave_max_f32(zh);
  if (lane == 63) {
    gred[wid][0] = xl; gred[wid][1] = xh; gred[wid][2] = yl;
    gred[wid][3] = yh; gred[wid][4] = zl; gred[wid][5] = zh;
  }
  if (tid < 64) { cnt64[tid] = 0; cur64[tid] = 0; }
  __syncthreads();
  float gx0 = gred[0][0], gx1 = gred[0][1], gy0 = gred[0][2];
  float gy1 = gred[0][3], gz0 = gred[0][4], gz1 = gred[0][5];
#pragma unroll
  for (int w = 1; w < 8; ++w) {
    gx0 = fminf(gx0, gred[w][0]); gx1 = fmaxf(gx1, gred[w][1]);
    gy0 = fminf(gy0, gred[w][2]); gy1 = fmaxf(gy1, gred[w][3]);
    gz0 = fminf(gz0, gred[w][4]); gz1 = fmaxf(gz1, gred[w][5]);
  }
  const float sx = 4.f / fmaxf((gx1 - gx0) * 1.0001f, 1e-20f);
  const float sy = 4.f / fmaxf((gy1 - gy0) * 1.0001f, 1e-20f);
  const float sz = 4.f / fmaxf((gz1 - gz0) * 1.0001f, 1e-20f);

  // ---- 64-bin Morton histogram ----
  int bin[16];
#pragma unroll
  for (int j = 0; j < 16; ++j) {
    u32 qx = (u32)min(3, max(0, (int)((lx[j] - gx0) * sx)));
    u32 qy = (u32)min(3, max(0, (int)((ly[j] - gy0) * sy)));
    u32 qz = (u32)min(3, max(0, (int)((lz[j] - gz0) * sz)));
    bin[j] = (int)((sp2(qx) << 2) | (sp2(qy) << 1) | sp2(qz));
    atomicAdd(&cnt64[bin[j]], 1);
  }
  __syncthreads();
  if (tid == 0) {
    int s = 0;
#pragma unroll
    for (int k = 0; k < 64; ++k) { base64[k] = s; s += cnt64[k]; }
  }
  __syncthreads();
#pragma unroll
  for (int j = 0; j < 16; ++j) {
    int i = tid + 512 * j;
    int pos = base64[bin[j]] + atomicAdd(&cur64[bin[j]], 1);
    XYZ4[pos] = make_float4(lx[j], ly[j], lz[j], __uint_as_float((u32)i));
  }
  if (tid == 0) cent[b * NPOINT] = 0;
  __syncthreads();

  // ---- own 1024-pt slice into registers + wave bbox ----
  float px[16], py[16], pz[16], dist[16];
  u32 klo[16];
  float axl = 3e38f, axh = -3e38f, ayl = 3e38f, ayh = -3e38f, azl = 3e38f, azh = -3e38f;
#pragma unroll
  for (int j = 0; j < 16; ++j) {
    int p = wid * 1024 + lane + 64 * j;
    float4 v = XYZ4[p];
    px[j] = v.x; py[j] = v.y; pz[j] = v.z;
    dist[j] = 1e10f;
    klo[j] = ((8191u - __float_as_uint(v.w)) << 13) | (u32)p;
    axl = fminf(axl, v.x); axh = fmaxf(axh, v.x);
    ayl = fminf(ayl, v.y); ayh = fmaxf(ayh, v.y);
    azl = fminf(azl, v.z); azh = fmaxf(azh, v.z);
  }
  const float bx0 = bcast63(wave_min_f32(axl)), bx1 = bcast63(wave_max_f32(axh));
  const float by0 = bcast63(wave_min_f32(ayl)), by1 = bcast63(wave_max_f32(ayh));
  const float bz0 = bcast63(wave_min_f32(azl)), bz1 = bcast63(wave_max_f32(azh));

  float c1x = xb[0], c1y = xb[1], c1z = xb[2];  // pending centroid(s)
  float c2x = 0.f, c2y = 0.f, c2z = 0.f;
  int has2 = 0;
  u64 m1w = 0, m2w = 0;   // cached wave top-2 (valid after first dirty round)
  float dmax = 1e10f;
  int rp = 0;
  int it = 1;

  while (it < NPOINT) {
    // ---- wave-uniform skip test vs all pending centroids ----
    float ax = fmaxf(fmaxf(bx0 - c1x, c1x - bx1), 0.f);
    float ay = fmaxf(fmaxf(by0 - c1y, c1y - by1), 0.f);
    float az = fmaxf(fmaxf(bz0 - c1z, c1z - bz1), 0.f);
    float LB1 = ax * ax + ay * ay + az * az;
    int dirty = (LB1 <= dmax * 1.00002f) ? 1 : 0;
    if (has2) {
      float bx = fmaxf(fmaxf(bx0 - c2x, c2x - bx1), 0.f);
      float by = fmaxf(fmaxf(by0 - c2y, c2y - by1), 0.f);
      float bz = fmaxf(fmaxf(bz0 - c2z, c2z - bz1), 0.f);
      float LB2 = bx * bx + by * by + bz * bz;
      dirty |= (LB2 <= dmax * 1.00002f) ? 1 : 0;
    }
    dirty = __builtin_amdgcn_readfirstlane(dirty);

    if (dirty) {
      // ---- apply pending centroid(s): exact sequential-min order ----
      if (has2) {
#pragma unroll
        for (int j = 0; j < 16; ++j) {
          float dx = px[j] - c1x, dy = py[j] - c1y, dz = pz[j] - c1z;
          float dd = dx * dx + dy * dy + dz * dz;  // same expr as rounds 1-9
          float ex = px[j] - c2x, ey = py[j] - c2y, ez = pz[j] - c2z;
          float ee = ex * ex + ey * ey + ez * ez;
          dist[j] = fminf(fminf(dist[j], dd), ee);
        }
      } else {
#pragma unroll
        for (int j = 0; j < 16; ++j) {
          float dx = px[j] - c1x, dy = py[j] - c1y, dz = pz[j] - c1z;
          float dd = dx * dx + dy * dy + dz * dz;
          dist[j] = fminf(dist[j], dd);
        }
      }
      // ---- wave max (m1w) ----
      double key[16];
#pragma unroll
      for (int j = 0; j < 16; ++j)
        key[j] = __longlong_as_double(
            (long long)(((u64)__float_as_uint(dist[j]) << 32) | klo[j]));
#pragma unroll
      for (int s = 1; s < 16; s <<= 1) {
#pragma unroll
        for (int j = 0; j < 16; j += 2 * s) key[j] = MAXF64(key[j], key[j + s]);
      }
      double wk = wave_max_f64(key[0]);
      u64 wkb = (u64)__double_as_longlong(wk);
      u32 m1lo_ = (u32)__builtin_amdgcn_readlane((int)(u32)wkb, 63);
      u32 m1hi_ = (u32)__builtin_amdgcn_readlane((int)(u32)(wkb >> 32), 63);
      m1w = ((u64)m1hi_ << 32) | m1lo_;
      dmax = __uint_as_float(m1hi_);
      // ---- wave runner-up (m2w): rescan with the winner element masked ----
      double r2 = 0.0;
#pragma unroll
      for (int j = 0; j < 16; ++j) {
        double kj = __longlong_as_double(
            (long long)(((u64)__float_as_uint(dist[j]) << 32) | klo[j]));
        kj = (klo[j] == m1lo_) ? 0.0 : kj;  // klo unique -> masks only winner
        r2 = MAXF64(r2, kj);
      }
      double wk2 = wave_max_f64(r2);
      u64 wk2b = (u64)__double_as_longlong(wk2);
      u32 m2lo_ = (u32)__builtin_amdgcn_readlane((int)(u32)wk2b, 63);
      u32 m2hi_ = (u32)__builtin_amdgcn_readlane((int)(u32)(wk2b >> 32), 63);
      m2w = ((u64)m2hi_ << 32) | m2lo_;
    }
    if (lane == 63) {
      kbuf[rp][wid] = m1w;
      kbuf[rp][8 + wid] = m2w;
    }
    __syncthreads();  // the only barrier per round

    // ---- resolve global top-2 over the 16 posted keys ----
    u64 kv = kbuf[rp][lane & 15];
    double kd = __longlong_as_double((long long)kv);
    double kr = row16_max_f64(kd);
    u64 krb = (u64)__double_as_longlong(kr);
    u32 g1lo = (u32)__builtin_amdgcn_readlane((int)(u32)krb, 15);
    u32 g1hi = (u32)__builtin_amdgcn_readlane((int)(u32)(krb >> 32), 15);
    u64 g1 = ((u64)g1hi << 32) | g1lo;
    double kd2 = (kv == g1) ? 0.0 : kd;
    double kr2 = row16_max_f64(kd2);
    u64 kr2b = (u64)__double_as_longlong(kr2);
    u32 g2lo = (u32)__builtin_amdgcn_readlane((int)(u32)kr2b, 15);
    u32 g2hi = (u32)__builtin_amdgcn_readlane((int)(u32)(kr2b >> 32), 15);

    u32 pos1 = g1lo & 8191u;
    u32 pos2 = g2lo & 8191u;
    float4 cc1 = XYZ4[pos1];  // winner coords (broadcast b128)
    float4 cc2 = XYZ4[pos2];  // runner-up coords
    if (tid == 0) cent[b * NPOINT + it] = (int)(8191u - ((g1lo >> 13) & 8191u));

    // ---- exact speculation: does the runner-up survive c1's update? ----
    float qdx = cc2.x - cc1.x, qdy = cc2.y - cc1.y, qdz = cc2.z - cc1.z;
    float qdd = qdx * qdx + qdy * qdy + qdz * qdz;  // same expr as update
    float qdist = __uint_as_float(g2hi);
    float tq = fminf(qdist, qdd);
    int hit = (__float_as_uint(tq) == g2hi) && (it + 1 < NPOINT);

    c1x = cc1.x; c1y = cc1.y; c1z = cc1.z;
    if (hit) {
      if (tid == 0)
        cent[b * NPOINT + it + 1] = (int)(8191u - ((g2lo >> 13) & 8191u));
      c2x = cc2.x; c2y = cc2.y; c2z = cc2.z;
      has2 = 1;
      it += 2;
    } else {
      has2 = 0;
      it += 1;
    }
    rp ^= 1;
  }
}

// ---------------- Kernel 2: 16-NN per centroid + new_xyz gather ----------------
__global__ __launch_bounds__(256) void knn_kernel(const float* __restrict__ xyz,
                                                  const int* __restrict__ cent,
                                                  int* __restrict__ knn,
                                                  float* __restrict__ out_xyz) {
  const int pt = blockIdx.x;       // 0..16383
  const int b = pt >> 11;
  const int tid = threadIdx.x;
  const float* xb = xyz + (size_t)b * NPTS * 3;
  const int ci = cent[pt];
  const float mx = xb[ci * 3 + 0], my = xb[ci * 3 + 1], mz = xb[ci * 3 + 2];
  if (tid < 3) out_xyz[pt * 3 + tid] = xb[ci * 3 + tid];
  const float sm = mx * mx + my * my + mz * mz;

  float d[32];
  float lv = 3.0e38f;
  int lj = 0;
#pragma unroll
  for (int j = 0; j < 32; ++j) {
    int i = tid + 256 * j;
    float x = xb[i * 3 + 0], y = xb[i * 3 + 1], z = xb[i * 3 + 2];
    float dot = mx * x + my * y + mz * z;
    float sp = x * x + y * y + z * z;
    float dd = -2.0f * dot + sm + sp;   // same assoc as reference
    d[j] = dd;
    if (dd < lv) { lv = dd; lj = j; }
  }

  __shared__ __align__(16) u64 kbuf[2][4];
  const int lane = tid & 63;

  for (int p = 0; p < KNN_K; ++p) {
    u32 fb = __float_as_uint(lv);
    u32 mapped = (fb & 0x80000000u) ? ~fb : (fb | 0x80000000u);
    u32 idx = (u32)(tid + (lj << 8));
    u64 ik = ~(((u64)mapped << 32) | (u64)idx);
    u64 wk = wave_max_u64(ik);
    if (lane == 63) kbuf[p & 1][tid >> 6] = wk;
    __syncthreads();
    const ulonglong2* kb = (const ulonglong2*)&kbuf[p & 1][0];
    ulonglong2 q0 = kb[0], q1 = kb[1];
    u64 best = MAXU64(MAXU64(q0.x, q0.y), MAXU64(q1.x, q1.y));
    u32 widx = (u32)(~best);
    if (tid == 0) knn[pt * KNN_K + p] = (int)widx;
    if (tid == (int)(widx & 255u)) {
      int j0 = (int)(widx >> 8);
      float nlv = 3.0e38f;
      int nlj = 0;
#pragma unroll
      for (int j = 0; j < 32; ++j) {
        if (j == j0) d[j] = 3.0e38f;
        if (d[j] < nlv) { nlv = d[j]; nlj = j; }
      }
      lv = nlv; lj = nlj;
    }
  }
}

// ---------------- Kernel 3: gather+GEMM + BN partials + per-(pt,o) max/min ----------------
__global__ __launch_bounds__(256) void gemm_stats_kernel(const float* __restrict__ feat,
                                                         const float* __restrict__ W,
                                                         const int* __restrict__ knn,
                                                         float* __restrict__ part,
                                                         float* __restrict__ mxbuf,
                                                         float* __restrict__ mnbuf) {
  const int tid = threadIdx.x;
  const int o0 = (tid & 63) * 2;
  const int o1 = o0 + 1;
  const int grp = tid >> 6;
  __shared__ __align__(16) float g[128][CIN];
  __shared__ int kidx[128];
  __shared__ float sred[4][128];

  const int rowbase = blockIdx.x * 128;
  if (tid < 128) kidx[tid] = knn[rowbase + tid];

  float4 w0v[16], w1v[16];
  {
    const float4* wv0 = (const float4*)(W + (size_t)o0 * CIN);
    const float4* wv1 = (const float4*)(W + (size_t)o1 * CIN);
#pragma unroll
    for (int q = 0; q < 16; ++q) { w0v[q] = wv0[q]; w1v[q] = wv1[q]; }
  }
  __syncthreads();
#pragma unroll
  for (int s = 0; s < 8; ++s) {
    int v = tid + 256 * s;
    int row = v >> 4, q = v & 15;
    int gr = rowbase + row;
    int bb = gr >> 15;
    const float4* src = (const float4*)(feat + (size_t)(bb * NPTS + kidx[row]) * CIN);
    *((float4*)&g[row][q * 4]) = src[q];
  }
  __syncthreads();

  float s1_0 = 0.f, s2_0 = 0.f, s1_1 = 0.f, s2_1 = 0.f;
#pragma unroll
  for (int pp = 0; pp < 2; ++pp) {
    const int ptl = grp + pp * 4;
    float mx0 = -3.0e38f, mn0 = 3.0e38f, mx1 = -3.0e38f, mn1 = 3.0e38f;
#pragma unroll
    for (int k = 0; k < KNN_K; ++k) {
      const int row = ptl * 16 + k;
      float a0 = 0.f, a1 = 0.f;
#pragma unroll
      for (int q = 0; q < 16; ++q) {
        float4 a = *((const float4*)&g[row][q * 4]);
        a0 += w0v[q].x * a.x + w0v[q].y * a.y + w0v[q].z * a.z + w0v[q].w * a.w;
        a1 += w1v[q].x * a.x + w1v[q].y * a.y + w1v[q].z * a.z + w1v[q].w * a.w;
      }
      s1_0 += a0; s2_0 += a0 * a0; mx0 = fmaxf(mx0, a0); mn0 = fminf(mn0, a0);
      s1_1 += a1; s2_1 += a1 * a1; mx1 = fmaxf(mx1, a1); mn1 = fminf(mn1, a1);
    }
    const size_t pt = (size_t)blockIdx.x * 8 + ptl;
    mxbuf[pt * COUT + o0] = mx0;
    mxbuf[pt * COUT + o1] = mx1;
    mnbuf[pt * COUT + o0] = mn0;
    mnbuf[pt * COUT + o1] = mn1;
  }
  sred[grp][o0] = s1_0; sred[grp][o1] = s1_1;
  __syncthreads();
  if (tid < 128) {
    float t = sred[0][tid] + sred[1][tid] + sred[2][tid] + sred[3][tid];
    part[blockIdx.x * 256 + tid] = t;
  }
  __syncthreads();
  sred[grp][o0] = s2_0; sred[grp][o1] = s2_1;
  __syncthreads();
  if (tid < 128) {
    float t = sred[0][tid] + sred[1][tid] + sred[2][tid] + sred[3][tid];
    part[blockIdx.x * 256 + 128 + tid] = t;
  }
}

// ---------------- Kernel 4: reduce partials -> scale/shift per channel ----------------
__global__ __launch_bounds__(256) void bn_reduce_kernel(const float* __restrict__ part,
                                                        const float* __restrict__ gamma,
                                                        const float* __restrict__ beta,
                                                        float* __restrict__ stats) {
  const int o = blockIdx.x;
  const int tid = threadIdx.x;
  float s1 = 0.f, s2 = 0.f;
  for (int p = tid; p < 2048; p += 256) {
    s1 += part[p * 256 + o];
    s2 += part[p * 256 + 128 + o];
  }
  __shared__ float r1[256], r2[256];
  r1[tid] = s1; r2[tid] = s2;
  __syncthreads();
  for (int s = 128; s >= 1; s >>= 1) {
    if (tid < s) { r1[tid] += r1[tid + s]; r2[tid] += r2[tid + s]; }
    __syncthreads();
  }
  if (tid == 0) {
    const float n = (float)(NBATCH * NPOINT * KNN_K);
    float mean = r1[0] / n;
    float var = r2[0] / n - mean * mean;
    float inv = rsqrtf(var + 1e-5f);
    float sc = gamma[o] * inv;
    stats[o] = sc;
    stats[128 + o] = beta[o] - mean * sc;
  }
}

// ---------------- Kernel 5: finalize out = relu(sel*sc + sh) ----------------
__global__ __launch_bounds__(256) void finalize_kernel(float* __restrict__ out_feat,
                                                       const float* __restrict__ mnbuf,
                                                       const float* __restrict__ stats) {
  const int i = blockIdx.x * 256 + threadIdx.x;
  const int o = i & 127;
  const float sc = stats[o];
  const float sh = stats[128 + o];
  const float mx = out_feat[i];
  const float mn = mnbuf[i];
  const float sel = (sc >= 0.f) ? mx : mn;
  out_feat[i] = fmaxf(sel * sc + sh, 0.f);
}

extern "C" void kernel_launch(void* const* d_in, const int* in_sizes, int n_in,
                              void* d_out, int out_size, void* d_ws, size_t ws_size,
                              hipStream_t stream) {
  const float* xyz = (const float*)d_in[0];
  const float* feat = (const float*)d_in[1];
  const float* W = (const float*)d_in[2];
  const float* gamma = (const float*)d_in[3];
  const float* beta = (const float*)d_in[4];
  float* out = (float*)d_out;

  int* cent = (int*)d_ws;
  int* knn = cent + NBATCH * NPOINT;
  float* part = (float*)(knn + NBATCH * NPOINT * KNN_K);
  float* stats = part + 2048 * 256;
  float* mnbuf = stats + 256;

  float* out_xyz = out;
  float* out_feat = out + NBATCH * NPOINT * 3;

  hipLaunchKernelGGL(fps_kernel, dim3(NBATCH), dim3(512), 0, stream, xyz, cent);
  hipLaunchKernelGGL(knn_kernel, dim3(NBATCH * NPOINT), dim3(256), 0, stream,
                     xyz, cent, knn, out_xyz);
  hipLaunchKernelGGL(gemm_stats_kernel, dim3(2048), dim3(256), 0, stream,
                     feat, W, knn, part, out_feat, mnbuf);
  hipLaunchKernelGGL(bn_reduce_kernel, dim3(128), dim3(256), 0, stream,
                     part, gamma, beta, stats);
  hipLaunchKernelGGL(finalize_kernel, dim3(8192), dim3(256), 0, stream,
                     out_feat, mnbuf, stats);
}

// Round 11
// 2028.265 us; speedup vs baseline: 1.1059x; 1.1059x over previous
//
#include <hip/hip_runtime.h>
#include <stdint.h>

#define NPTS 8192
#define NBATCH 8
#define NPOINT 2048
#define KNN_K 16
#define CIN 64
#define COUT 128

typedef unsigned long long u64;
typedef unsigned int u32;

#define MAXU64(a, b) (((a) > (b)) ? (a) : (b))
#define MAXF64(a, b) fmax((a), (b))

// wave64 max-reduce of a positive-finite f64 key via DPP row_shr + row_bcast.
// Result valid in lane 63. Proven rounds 4-10.
__device__ __forceinline__ double wave_max_f64(double v) {
#define DPPSTEP(C)                                                             \
  {                                                                            \
    u64 k = (u64)__double_as_longlong(v);                                      \
    u32 lo = (u32)k, hi = (u32)(k >> 32);                                      \
    u32 nlo = (u32)__builtin_amdgcn_update_dpp(0, (int)lo, C, 0xf, 0xf, true); \
    u32 nhi = (u32)__builtin_amdgcn_update_dpp(0, (int)hi, C, 0xf, 0xf, true); \
    double o = __longlong_as_double((long long)(((u64)nhi << 32) | nlo));      \
    v = fmax(v, o);                                                            \
  }
  DPPSTEP(0x111)
  DPPSTEP(0x112)
  DPPSTEP(0x114)
  DPPSTEP(0x118)
  DPPSTEP(0x142)
  DPPSTEP(0x143)
#undef DPPSTEP
  return v;
}

// 8-lane (row_shr 1/2/4) f64 max: lane 7 of each 8-group holds max of lanes 0..7.
__device__ __forceinline__ double row8_max_f64(double v) {
#define DPPSTEP(C)                                                             \
  {                                                                            \
    u64 k = (u64)__double_as_longlong(v);                                      \
    u32 lo = (u32)k, hi = (u32)(k >> 32);                                      \
    u32 nlo = (u32)__builtin_amdgcn_update_dpp(0, (int)lo, C, 0xf, 0xf, true); \
    u32 nhi = (u32)__builtin_amdgcn_update_dpp(0, (int)hi, C, 0xf, 0xf, true); \
    double o = __longlong_as_double((long long)(((u64)nhi << 32) | nlo));      \
    v = fmax(v, o);                                                            \
  }
  DPPSTEP(0x111)
  DPPSTEP(0x112)
  DPPSTEP(0x114)
#undef DPPSTEP
  return v;
}

// wave64 max-reduce on exact u64 keys (for knn). Valid in lane 63.
__device__ __forceinline__ u64 wave_max_u64(u64 k) {
  u32 lo = (u32)k, hi = (u32)(k >> 32);
#define DPPSTEP(C)                                                             \
  {                                                                            \
    u32 nlo = (u32)__builtin_amdgcn_update_dpp(0, (int)lo, C, 0xf, 0xf, true); \
    u32 nhi = (u32)__builtin_amdgcn_update_dpp(0, (int)hi, C, 0xf, 0xf, true); \
    u64 cur = ((u64)hi << 32) | lo;                                            \
    u64 oth = ((u64)nhi << 32) | nlo;                                          \
    if (oth > cur) { hi = nhi; lo = nlo; }                                     \
  }
  DPPSTEP(0x111)
  DPPSTEP(0x112)
  DPPSTEP(0x114)
  DPPSTEP(0x118)
  DPPSTEP(0x142)
  DPPSTEP(0x143)
#undef DPPSTEP
  return ((u64)hi << 32) | lo;
}

// wave64 min/max f32, invalid lanes keep own value (bound_ctrl=false).
__device__ __forceinline__ float wave_min_f32(float v) {
#define STEP(C)                                                                \
  {                                                                            \
    int o = __builtin_amdgcn_update_dpp((int)__float_as_uint(v),               \
                                        (int)__float_as_uint(v), C, 0xf, 0xf,  \
                                        false);                                \
    v = fminf(v, __uint_as_float((u32)o));                                     \
  }
  STEP(0x111) STEP(0x112) STEP(0x114) STEP(0x118) STEP(0x142) STEP(0x143)
#undef STEP
  return v;
}
__device__ __forceinline__ float wave_max_f32(float v) {
#define STEP(C)                                                                \
  {                                                                            \
    int o = __builtin_amdgcn_update_dpp((int)__float_as_uint(v),               \
                                        (int)__float_as_uint(v), C, 0xf, 0xf,  \
                                        false);                                \
    v = fmaxf(v, __uint_as_float((u32)o));                                     \
  }
  STEP(0x111) STEP(0x112) STEP(0x114) STEP(0x118) STEP(0x142) STEP(0x143)
#undef STEP
  return v;
}

__device__ __forceinline__ float bcast63(float v) {
  return __uint_as_float(
      (u32)__builtin_amdgcn_readlane((int)__float_as_uint(v), 63));
}

__device__ __forceinline__ u32 sp2(u32 v) {  // 2 bits -> bits 0,3
  return (v & 1u) | ((v & 2u) << 2);
}

// ---------------- Kernel 1: FPS (round-9 best: 1515 us, proven) -------------
// grid NBATCH, block 512. Morton counting-sort (64 bins) into LDS float4
// XYZ4[pos] = {x,y,z,orig_bits}; wave w owns sorted slice [1024w,1024w+1024)
// in REGISTERS (16 pts/thread) with its true bbox + bit-exact skip.
// Per iter DS ops/wave: 1 key write + 1 b64 key read + 1 b128 coord read.
// Key = (dist_bits<<32)|((8191-orig)<<13)|pos : argmax, first-orig tie-break.
__global__ __launch_bounds__(512) void fps_kernel(const float* __restrict__ xyz,
                                                  int* __restrict__ cent) {
  const int b = blockIdx.x;
  const int tid = threadIdx.x;
  const int lane = tid & 63;
  const int wid = tid >> 6;  // 0..7
  const float* xb = xyz + (size_t)b * NPTS * 3;

  __shared__ __align__(16) float4 XYZ4[NPTS];      // 128 KB
  __shared__ float gred[8][6];
  __shared__ int cnt64[64], base64[64], cur64[64];
  __shared__ __align__(16) double kbuf[2][8];

  // ---- load 16 pts/thread + global bbox ----
  float lx[16], ly[16], lz[16];
  float xl = 3e38f, xh = -3e38f, yl = 3e38f, yh = -3e38f, zl = 3e38f, zh = -3e38f;
#pragma unroll
  for (int j = 0; j < 16; ++j) {
    int i = tid + 512 * j;
    float x = xb[i * 3 + 0], y = xb[i * 3 + 1], z = xb[i * 3 + 2];
    lx[j] = x; ly[j] = y; lz[j] = z;
    xl = fminf(xl, x); xh = fmaxf(xh, x);
    yl = fminf(yl, y); yh = fmaxf(yh, y);
    zl = fminf(zl, z); zh = fmaxf(zh, z);
  }
  xl = wave_min_f32(xl); xh = wave_max_f32(xh);
  yl = wave_min_f32(yl); yh = wave_max_f32(yh);
  zl = wave_min_f32(zl); zh = wave_max_f32(zh);
  if (lane == 63) {
    gred[wid][0] = xl; gred[wid][1] = xh; gred[wid][2] = yl;
    gred[wid][3] = yh; gred[wid][4] = zl; gred[wid][5] = zh;
  }
  if (tid < 64) { cnt64[tid] = 0; cur64[tid] = 0; }
  __syncthreads();
  float gx0 = gred[0][0], gx1 = gred[0][1], gy0 = gred[0][2];
  float gy1 = gred[0][3], gz0 = gred[0][4], gz1 = gred[0][5];
#pragma unroll
  for (int w = 1; w < 8; ++w) {
    gx0 = fminf(gx0, gred[w][0]); gx1 = fmaxf(gx1, gred[w][1]);
    gy0 = fminf(gy0, gred[w][2]); gy1 = fmaxf(gy1, gred[w][3]);
    gz0 = fminf(gz0, gred[w][4]); gz1 = fmaxf(gz1, gred[w][5]);
  }
  const float sx = 4.f / fmaxf((gx1 - gx0) * 1.0001f, 1e-20f);
  const float sy = 4.f / fmaxf((gy1 - gy0) * 1.0001f, 1e-20f);
  const float sz = 4.f / fmaxf((gz1 - gz0) * 1.0001f, 1e-20f);

  // ---- 64-bin Morton histogram ----
  int bin[16];
#pragma unroll
  for (int j = 0; j < 16; ++j) {
    u32 qx = (u32)min(3, max(0, (int)((lx[j] - gx0) * sx)));
    u32 qy = (u32)min(3, max(0, (int)((ly[j] - gy0) * sy)));
    u32 qz = (u32)min(3, max(0, (int)((lz[j] - gz0) * sz)));
    bin[j] = (int)((sp2(qx) << 2) | (sp2(qy) << 1) | sp2(qz));
    atomicAdd(&cnt64[bin[j]], 1);
  }
  __syncthreads();
  if (tid == 0) {
    int s = 0;
#pragma unroll
    for (int k = 0; k < 64; ++k) { base64[k] = s; s += cnt64[k]; }
  }
  __syncthreads();
  // ---- scatter into sorted float4 SoA ----
#pragma unroll
  for (int j = 0; j < 16; ++j) {
    int i = tid + 512 * j;
    int pos = base64[bin[j]] + atomicAdd(&cur64[bin[j]], 1);
    XYZ4[pos] = make_float4(lx[j], ly[j], lz[j], __uint_as_float((u32)i));
  }
  if (tid == 0) cent[b * NPOINT] = 0;
  __syncthreads();

  // ---- own 1024-pt slice into registers + wave bbox ----
  float px[16], py[16], pz[16], dist[16];
  u32 klo[16];
  float axl = 3e38f, axh = -3e38f, ayl = 3e38f, ayh = -3e38f, azl = 3e38f, azh = -3e38f;
#pragma unroll
  for (int j = 0; j < 16; ++j) {
    int p = wid * 1024 + lane + 64 * j;
    float4 v = XYZ4[p];
    px[j] = v.x; py[j] = v.y; pz[j] = v.z;
    dist[j] = 1e10f;
    klo[j] = ((8191u - __float_as_uint(v.w)) << 13) | (u32)p;
    axl = fminf(axl, v.x); axh = fmaxf(axh, v.x);
    ayl = fminf(ayl, v.y); ayh = fmaxf(ayh, v.y);
    azl = fminf(azl, v.z); azh = fmaxf(azh, v.z);
  }
  const float bx0 = bcast63(wave_min_f32(axl)), bx1 = bcast63(wave_max_f32(axh));
  const float by0 = bcast63(wave_min_f32(ayl)), by1 = bcast63(wave_max_f32(ayh));
  const float bz0 = bcast63(wave_min_f32(azl)), bz1 = bcast63(wave_max_f32(azh));

  float cx = xb[0], cy = xb[1], cz = xb[2];  // centroid 0 = point 0
  float dmax = 1e10f;
  double prev_wk = 0.0;  // lane 63's copy is authoritative

  for (int it = 1; it < NPOINT; ++it) {
    // wave-local exact skip test (bit-exact no-op skip, proven r5-r10)
    float ax = fmaxf(fmaxf(bx0 - cx, cx - bx1), 0.f);
    float ay = fmaxf(fmaxf(by0 - cy, cy - by1), 0.f);
    float az = fmaxf(fmaxf(bz0 - cz, cz - bz1), 0.f);
    float LB = ax * ax + ay * ay + az * az;
    int skip = (LB > dmax * 1.00002f) ? 1 : 0;
    skip = __builtin_amdgcn_readfirstlane(skip);
    double wk;
    if (skip) {
      wk = prev_wk;
    } else {
      double key[16];
#pragma unroll
      for (int j = 0; j < 16; ++j) {
        float dx = px[j] - cx, dy = py[j] - cy, dz = pz[j] - cz;
        float dd = dx * dx + dy * dy + dz * dz;  // same expr as rounds 1-10
        float t = fminf(dist[j], dd);
        dist[j] = t;
        key[j] = __longlong_as_double(
            (long long)(((u64)__float_as_uint(t) << 32) | klo[j]));
      }
#pragma unroll
      for (int s = 1; s < 16; s <<= 1) {
#pragma unroll
        for (int j = 0; j < 16; j += 2 * s) key[j] = MAXF64(key[j], key[j + s]);
      }
      wk = wave_max_f64(key[0]);  // lane 63 owns the wave max
      prev_wk = wk;
      dmax = __uint_as_float((u32)__builtin_amdgcn_readlane(
          (int)(u32)(((u64)__double_as_longlong(wk)) >> 32), 63));
    }
    if (lane == 63) kbuf[it & 1][wid] = wk;  // 1 ds_write_b64
    __syncthreads();  // the only barrier per iteration
    // light resolve: 1 ds_read_b64 per lane + 3-step row8 DPP + readlane(7)
    double kv = kbuf[it & 1][lane & 7];
    kv = row8_max_f64(kv);
    u32 rlo = (u32)__builtin_amdgcn_readlane(
        (int)(u32)(u64)__double_as_longlong(kv), 7);
    u32 pos = rlo & 8191u;
    if (tid == 0) cent[b * NPOINT + it] = (int)(8191u - ((rlo >> 13) & 8191u));
    float4 c4 = XYZ4[pos];  // 1 ds_read_b128 broadcast
    cx = c4.x; cy = c4.y; cz = c4.z;
  }
}

// ---------------- Kernel 2: 16-NN, wave-local extraction + single merge -----
// grid NBATCH*NPOINT, block 256 (4 waves). Wave w owns points [2048w,2048w+2048)
// (32/lane in registers). Each wave extracts ITS top-16 (ascending (d,idx))
// with NO barriers (in-wave DPP reduce + owner rescan). One barrier, then
// wave 0 merges the 4x16 candidates: 16 in-wave max-extractions over 64 lanes
// (keys unique -> identical selection set/order as the block-wide version:
// any global top-16 member is in its own wave's top-16).
__global__ __launch_bounds__(256) void knn_kernel(const float* __restrict__ xyz,
                                                  const int* __restrict__ cent,
                                                  int* __restrict__ knn,
                                                  float* __restrict__ out_xyz) {
  const int pt = blockIdx.x;       // 0..16383
  const int b = pt >> 11;
  const int tid = threadIdx.x;
  const int lane = tid & 63;
  const int wid = tid >> 6;        // 0..3
  const float* xb = xyz + (size_t)b * NPTS * 3;
  const int ci = cent[pt];
  const float mx = xb[ci * 3 + 0], my = xb[ci * 3 + 1], mz = xb[ci * 3 + 2];
  if (tid < 3) out_xyz[pt * 3 + tid] = xb[ci * 3 + tid];
  const float sm = mx * mx + my * my + mz * mz;

  // wave w's candidate block: indices wid*2048 + lane + 64*j, j=0..31
  float d[32];
  float lv = 3.0e38f;
  int lj = 0;
#pragma unroll
  for (int j = 0; j < 32; ++j) {
    int i = wid * 2048 + lane + 64 * j;
    float x = xb[i * 3 + 0], y = xb[i * 3 + 1], z = xb[i * 3 + 2];
    float dot = mx * x + my * y + mz * z;
    float sp = x * x + y * y + z * z;
    float dd = -2.0f * dot + sm + sp;   // same assoc as reference (r1-r10)
    d[j] = dd;
    if (dd < lv) { lv = dd; lj = j; }
  }

  __shared__ __align__(16) u64 kw[4][KNN_K];

  // ---- wave-local extraction of top-16 (no barriers) ----
  for (int p = 0; p < KNN_K; ++p) {
    u32 fb = __float_as_uint(lv);
    u32 mapped = (fb & 0x80000000u) ? ~fb : (fb | 0x80000000u);  // order-preserving
    u32 idx = (u32)(wid * 2048 + lane + (lj << 6));  // == point index
    // min-key (smaller d, then smaller idx) == max of inverted key
    u64 ik = ~(((u64)mapped << 32) | (u64)idx);
    u64 wk = wave_max_u64(ik);  // valid lane 63
    u32 wlo = (u32)__builtin_amdgcn_readlane((int)(u32)wk, 63);
    u32 whi = (u32)__builtin_amdgcn_readlane((int)(u32)(wk >> 32), 63);
    if (lane == 63) kw[wid][p] = ((u64)whi << 32) | wlo;
    u32 widx = ~wlo;  // winner's point index
    // owner (in this wave by construction) removes winner and rescans
    if (lane == (int)(widx & 63u)) {
      int j0 = (int)((widx >> 6) & 31u);
      float nlv = 3.0e38f;
      int nlj = 0;
#pragma unroll
      for (int j = 0; j < 32; ++j) {
        if (j == j0) d[j] = 3.0e38f;
        if (d[j] < nlv) { nlv = d[j]; nlj = j; }
      }
      lv = nlv; lj = nlj;
    }
  }
  __syncthreads();  // the only barrier

  // ---- wave 0 merges 4x16 -> global top-16 ----
  if (wid == 0) {
    u64 k = kw[lane >> 4][lane & 15];
    for (int p = 0; p < KNN_K; ++p) {
      u64 m = wave_max_u64(k);
      u32 mlo = (u32)__builtin_amdgcn_readlane((int)(u32)m, 63);
      u32 mhi = (u32)__builtin_amdgcn_readlane((int)(u32)(m >> 32), 63);
      if (lane == 0) knn[pt * KNN_K + p] = (int)(~mlo);
      if (k == (((u64)mhi << 32) | mlo)) k = 0;  // self-mask (keys unique)
    }
  }
}

// ---------------- Kernel 3: gather+GEMM + BN partials + per-(pt,o) max/min ----------------
__global__ __launch_bounds__(256) void gemm_stats_kernel(const float* __restrict__ feat,
                                                         const float* __restrict__ W,
                                                         const int* __restrict__ knn,
                                                         float* __restrict__ part,
                                                         float* __restrict__ mxbuf,
                                                         float* __restrict__ mnbuf) {
  const int tid = threadIdx.x;
  const int o0 = (tid & 63) * 2;
  const int o1 = o0 + 1;
  const int grp = tid >> 6;
  __shared__ __align__(16) float g[128][CIN];
  __shared__ int kidx[128];
  __shared__ float sred[4][128];

  const int rowbase = blockIdx.x * 128;
  if (tid < 128) kidx[tid] = knn[rowbase + tid];

  float4 w0v[16], w1v[16];
  {
    const float4* wv0 = (const float4*)(W + (size_t)o0 * CIN);
    const float4* wv1 = (const float4*)(W + (size_t)o1 * CIN);
#pragma unroll
    for (int q = 0; q < 16; ++q) { w0v[q] = wv0[q]; w1v[q] = wv1[q]; }
  }
  __syncthreads();
#pragma unroll
  for (int s = 0; s < 8; ++s) {
    int v = tid + 256 * s;
    int row = v >> 4, q = v & 15;
    int gr = rowbase + row;
    int bb = gr >> 15;
    const float4* src = (const float4*)(feat + (size_t)(bb * NPTS + kidx[row]) * CIN);
    *((float4*)&g[row][q * 4]) = src[q];
  }
  __syncthreads();

  float s1_0 = 0.f, s2_0 = 0.f, s1_1 = 0.f, s2_1 = 0.f;
#pragma unroll
  for (int pp = 0; pp < 2; ++pp) {
    const int ptl = grp + pp * 4;
    float mx0 = -3.0e38f, mn0 = 3.0e38f, mx1 = -3.0e38f, mn1 = 3.0e38f;
#pragma unroll
    for (int k = 0; k < KNN_K; ++k) {
      const int row = ptl * 16 + k;
      float a0 = 0.f, a1 = 0.f;
#pragma unroll
      for (int q = 0; q < 16; ++q) {
        float4 a = *((const float4*)&g[row][q * 4]);
        a0 += w0v[q].x * a.x + w0v[q].y * a.y + w0v[q].z * a.z + w0v[q].w * a.w;
        a1 += w1v[q].x * a.x + w1v[q].y * a.y + w1v[q].z * a.z + w1v[q].w * a.w;
      }
      s1_0 += a0; s2_0 += a0 * a0; mx0 = fmaxf(mx0, a0); mn0 = fminf(mn0, a0);
      s1_1 += a1; s2_1 += a1 * a1; mx1 = fmaxf(mx1, a1); mn1 = fminf(mn1, a1);
    }
    const size_t pt = (size_t)blockIdx.x * 8 + ptl;
    mxbuf[pt * COUT + o0] = mx0;
    mxbuf[pt * COUT + o1] = mx1;
    mnbuf[pt * COUT + o0] = mn0;
    mnbuf[pt * COUT + o1] = mn1;
  }
  sred[grp][o0] = s1_0; sred[grp][o1] = s1_1;
  __syncthreads();
  if (tid < 128) {
    float t = sred[0][tid] + sred[1][tid] + sred[2][tid] + sred[3][tid];
    part[blockIdx.x * 256 + tid] = t;
  }
  __syncthreads();
  sred[grp][o0] = s2_0; sred[grp][o1] = s2_1;
  __syncthreads();
  if (tid < 128) {
    float t = sred[0][tid] + sred[1][tid] + sred[2][tid] + sred[3][tid];
    part[blockIdx.x * 256 + 128 + tid] = t;
  }
}

// ---------------- Kernel 4: reduce partials -> scale/shift per channel ----------------
__global__ __launch_bounds__(256) void bn_reduce_kernel(const float* __restrict__ part,
                                                        const float* __restrict__ gamma,
                                                        const float* __restrict__ beta,
                                                        float* __restrict__ stats) {
  const int o = blockIdx.x;
  const int tid = threadIdx.x;
  float s1 = 0.f, s2 = 0.f;
  for (int p = tid; p < 2048; p += 256) {
    s1 += part[p * 256 + o];
    s2 += part[p * 256 + 128 + o];
  }
  __shared__ float r1[256], r2[256];
  r1[tid] = s1; r2[tid] = s2;
  __syncthreads();
  for (int s = 128; s >= 1; s >>= 1) {
    if (tid < s) { r1[tid] += r1[tid + s]; r2[tid] += r2[tid + s]; }
    __syncthreads();
  }
  if (tid == 0) {
    const float n = (float)(NBATCH * NPOINT * KNN_K);
    float mean = r1[0] / n;
    float var = r2[0] / n - mean * mean;
    float inv = rsqrtf(var + 1e-5f);
    float sc = gamma[o] * inv;
    stats[o] = sc;
    stats[128 + o] = beta[o] - mean * sc;
  }
}

// ---------------- Kernel 5: finalize out = relu(sel*sc + sh) ----------------
__global__ __launch_bounds__(256) void finalize_kernel(float* __restrict__ out_feat,
                                                       const float* __restrict__ mnbuf,
                                                       const float* __restrict__ stats) {
  const int i = blockIdx.x * 256 + threadIdx.x;
  const int o = i & 127;
  const float sc = stats[o];
  const float sh = stats[128 + o];
  const float mx = out_feat[i];
  const float mn = mnbuf[i];
  const float sel = (sc >= 0.f) ? mx : mn;
  out_feat[i] = fmaxf(sel * sc + sh, 0.f);
}

extern "C" void kernel_launch(void* const* d_in, const int* in_sizes, int n_in,
                              void* d_out, int out_size, void* d_ws, size_t ws_size,
                              hipStream_t stream) {
  const float* xyz = (const float*)d_in[0];
  const float* feat = (const float*)d_in[1];
  const float* W = (const float*)d_in[2];
  const float* gamma = (const float*)d_in[3];
  const float* beta = (const float*)d_in[4];
  float* out = (float*)d_out;

  int* cent = (int*)d_ws;
  int* knn = cent + NBATCH * NPOINT;
  float* part = (float*)(knn + NBATCH * NPOINT * KNN_K);
  float* stats = part + 2048 * 256;
  float* mnbuf = stats + 256;

  float* out_xyz = out;
  float* out_feat = out + NBATCH * NPOINT * 3;

  hipLaunchKernelGGL(fps_kernel, dim3(NBATCH), dim3(512), 0, stream, xyz, cent);
  hipLaunchKernelGGL(knn_kernel, dim3(NBATCH * NPOINT), dim3(256), 0, stream,
                     xyz, cent, knn, out_xyz);
  hipLaunchKernelGGL(gemm_stats_kernel, dim3(2048), dim3(256), 0, stream,
                     feat, W, knn, part, out_feat, mnbuf);
  hipLaunchKernelGGL(bn_reduce_kernel, dim3(128), dim3(256), 0, stream,
                     part, gamma, beta, stats);
  hipLaunchKernelGGL(finalize_kernel, dim3(8192), dim3(256), 0, stream,
                     out_feat, mnbuf, stats);
}

// Round 12
// 1998.118 us; speedup vs baseline: 1.1226x; 1.0151x over previous
//
#include <hip/hip_runtime.h>
#include <stdint.h>

#define NPTS 8192
#define NBATCH 8
#define NPOINT 2048
#define KNN_K 16
#define CIN 64
#define COUT 128

typedef unsigned long long u64;
typedef unsigned int u32;

#define MAXU64(a, b) (((a) > (b)) ? (a) : (b))
#define MAXF64(a, b) fmax((a), (b))

// wave64 max-reduce of a positive-finite f64 key via DPP row_shr + row_bcast.
// Result valid in lane 63. Proven rounds 4-11.
__device__ __forceinline__ double wave_max_f64(double v) {
#define DPPSTEP(C)                                                             \
  {                                                                            \
    u64 k = (u64)__double_as_longlong(v);                                      \
    u32 lo = (u32)k, hi = (u32)(k >> 32);                                      \
    u32 nlo = (u32)__builtin_amdgcn_update_dpp(0, (int)lo, C, 0xf, 0xf, true); \
    u32 nhi = (u32)__builtin_amdgcn_update_dpp(0, (int)hi, C, 0xf, 0xf, true); \
    double o = __longlong_as_double((long long)(((u64)nhi << 32) | nlo));      \
    v = fmax(v, o);                                                            \
  }
  DPPSTEP(0x111)
  DPPSTEP(0x112)
  DPPSTEP(0x114)
  DPPSTEP(0x118)
  DPPSTEP(0x142)
  DPPSTEP(0x143)
#undef DPPSTEP
  return v;
}

// 8-lane (row_shr 1/2/4) f64 max: lane 7 of each 8-group holds max of lanes 0..7.
__device__ __forceinline__ double row8_max_f64(double v) {
#define DPPSTEP(C)                                                             \
  {                                                                            \
    u64 k = (u64)__double_as_longlong(v);                                      \
    u32 lo = (u32)k, hi = (u32)(k >> 32);                                      \
    u32 nlo = (u32)__builtin_amdgcn_update_dpp(0, (int)lo, C, 0xf, 0xf, true); \
    u32 nhi = (u32)__builtin_amdgcn_update_dpp(0, (int)hi, C, 0xf, 0xf, true); \
    double o = __longlong_as_double((long long)(((u64)nhi << 32) | nlo));      \
    v = fmax(v, o);                                                            \
  }
  DPPSTEP(0x111)
  DPPSTEP(0x112)
  DPPSTEP(0x114)
#undef DPPSTEP
  return v;
}

// wave64 max-reduce on exact u64 keys (for knn). Valid in lane 63.
__device__ __forceinline__ u64 wave_max_u64(u64 k) {
  u32 lo = (u32)k, hi = (u32)(k >> 32);
#define DPPSTEP(C)                                                             \
  {                                                                            \
    u32 nlo = (u32)__builtin_amdgcn_update_dpp(0, (int)lo, C, 0xf, 0xf, true); \
    u32 nhi = (u32)__builtin_amdgcn_update_dpp(0, (int)hi, C, 0xf, 0xf, true); \
    u64 cur = ((u64)hi << 32) | lo;                                            \
    u64 oth = ((u64)nhi << 32) | nlo;                                          \
    if (oth > cur) { hi = nhi; lo = nlo; }                                     \
  }
  DPPSTEP(0x111)
  DPPSTEP(0x112)
  DPPSTEP(0x114)
  DPPSTEP(0x118)
  DPPSTEP(0x142)
  DPPSTEP(0x143)
#undef DPPSTEP
  return ((u64)hi << 32) | lo;
}

// wave64 min/max f32, invalid lanes keep own value (bound_ctrl=false).
__device__ __forceinline__ float wave_min_f32(float v) {
#define STEP(C)                                                                \
  {                                                                            \
    int o = __builtin_amdgcn_update_dpp((int)__float_as_uint(v),               \
                                        (int)__float_as_uint(v), C, 0xf, 0xf,  \
                                        false);                                \
    v = fminf(v, __uint_as_float((u32)o));                                     \
  }
  STEP(0x111) STEP(0x112) STEP(0x114) STEP(0x118) STEP(0x142) STEP(0x143)
#undef STEP
  return v;
}
__device__ __forceinline__ float wave_max_f32(float v) {
#define STEP(C)                                                                \
  {                                                                            \
    int o = __builtin_amdgcn_update_dpp((int)__float_as_uint(v),               \
                                        (int)__float_as_uint(v), C, 0xf, 0xf,  \
                                        false);                                \
    v = fmaxf(v, __uint_as_float((u32)o));                                     \
  }
  STEP(0x111) STEP(0x112) STEP(0x114) STEP(0x118) STEP(0x142) STEP(0x143)
#undef STEP
  return v;
}

__device__ __forceinline__ float bcast63(float v) {
  return __uint_as_float(
      (u32)__builtin_amdgcn_readlane((int)__float_as_uint(v), 63));
}

__device__ __forceinline__ u32 sp2(u32 v) {  // 2 bits -> bits 0,3
  return (v & 1u) | ((v & 2u) << 2);
}

// ---------------- Kernel 1: FPS (round-9 best: 1515 us, proven) -------------
// grid NBATCH, block 512. Morton counting-sort (64 bins) into LDS float4
// XYZ4[pos] = {x,y,z,orig_bits}; wave w owns sorted slice [1024w,1024w+1024)
// in REGISTERS (16 pts/thread) with its true bbox + bit-exact skip.
// Per iter DS ops/wave: 1 key write + 1 b64 key read + 1 b128 coord read.
// Key = (dist_bits<<32)|((8191-orig)<<13)|pos : argmax, first-orig tie-break.
__global__ __launch_bounds__(512) void fps_kernel(const float* __restrict__ xyz,
                                                  int* __restrict__ cent) {
  const int b = blockIdx.x;
  const int tid = threadIdx.x;
  const int lane = tid & 63;
  const int wid = tid >> 6;  // 0..7
  const float* xb = xyz + (size_t)b * NPTS * 3;

  __shared__ __align__(16) float4 XYZ4[NPTS];      // 128 KB
  __shared__ float gred[8][6];
  __shared__ int cnt64[64], base64[64], cur64[64];
  __shared__ __align__(16) double kbuf[2][8];

  // ---- load 16 pts/thread + global bbox ----
  float lx[16], ly[16], lz[16];
  float xl = 3e38f, xh = -3e38f, yl = 3e38f, yh = -3e38f, zl = 3e38f, zh = -3e38f;
#pragma unroll
  for (int j = 0; j < 16; ++j) {
    int i = tid + 512 * j;
    float x = xb[i * 3 + 0], y = xb[i * 3 + 1], z = xb[i * 3 + 2];
    lx[j] = x; ly[j] = y; lz[j] = z;
    xl = fminf(xl, x); xh = fmaxf(xh, x);
    yl = fminf(yl, y); yh = fmaxf(yh, y);
    zl = fminf(zl, z); zh = fmaxf(zh, z);
  }
  xl = wave_min_f32(xl); xh = wave_max_f32(xh);
  yl = wave_min_f32(yl); yh = wave_max_f32(yh);
  zl = wave_min_f32(zl); zh = wave_max_f32(zh);
  if (lane == 63) {
    gred[wid][0] = xl; gred[wid][1] = xh; gred[wid][2] = yl;
    gred[wid][3] = yh; gred[wid][4] = zl; gred[wid][5] = zh;
  }
  if (tid < 64) { cnt64[tid] = 0; cur64[tid] = 0; }
  __syncthreads();
  float gx0 = gred[0][0], gx1 = gred[0][1], gy0 = gred[0][2];
  float gy1 = gred[0][3], gz0 = gred[0][4], gz1 = gred[0][5];
#pragma unroll
  for (int w = 1; w < 8; ++w) {
    gx0 = fminf(gx0, gred[w][0]); gx1 = fmaxf(gx1, gred[w][1]);
    gy0 = fminf(gy0, gred[w][2]); gy1 = fmaxf(gy1, gred[w][3]);
    gz0 = fminf(gz0, gred[w][4]); gz1 = fmaxf(gz1, gred[w][5]);
  }
  const float sx = 4.f / fmaxf((gx1 - gx0) * 1.0001f, 1e-20f);
  const float sy = 4.f / fmaxf((gy1 - gy0) * 1.0001f, 1e-20f);
  const float sz = 4.f / fmaxf((gz1 - gz0) * 1.0001f, 1e-20f);

  // ---- 64-bin Morton histogram ----
  int bin[16];
#pragma unroll
  for (int j = 0; j < 16; ++j) {
    u32 qx = (u32)min(3, max(0, (int)((lx[j] - gx0) * sx)));
    u32 qy = (u32)min(3, max(0, (int)((ly[j] - gy0) * sy)));
    u32 qz = (u32)min(3, max(0, (int)((lz[j] - gz0) * sz)));
    bin[j] = (int)((sp2(qx) << 2) | (sp2(qy) << 1) | sp2(qz));
    atomicAdd(&cnt64[bin[j]], 1);
  }
  __syncthreads();
  if (tid == 0) {
    int s = 0;
#pragma unroll
    for (int k = 0; k < 64; ++k) { base64[k] = s; s += cnt64[k]; }
  }
  __syncthreads();
  // ---- scatter into sorted float4 SoA ----
#pragma unroll
  for (int j = 0; j < 16; ++j) {
    int i = tid + 512 * j;
    int pos = base64[bin[j]] + atomicAdd(&cur64[bin[j]], 1);
    XYZ4[pos] = make_float4(lx[j], ly[j], lz[j], __uint_as_float((u32)i));
  }
  if (tid == 0) cent[b * NPOINT] = 0;
  __syncthreads();

  // ---- own 1024-pt slice into registers + wave bbox ----
  float px[16], py[16], pz[16], dist[16];
  u32 klo[16];
  float axl = 3e38f, axh = -3e38f, ayl = 3e38f, ayh = -3e38f, azl = 3e38f, azh = -3e38f;
#pragma unroll
  for (int j = 0; j < 16; ++j) {
    int p = wid * 1024 + lane + 64 * j;
    float4 v = XYZ4[p];
    px[j] = v.x; py[j] = v.y; pz[j] = v.z;
    dist[j] = 1e10f;
    klo[j] = ((8191u - __float_as_uint(v.w)) << 13) | (u32)p;
    axl = fminf(axl, v.x); axh = fmaxf(axh, v.x);
    ayl = fminf(ayl, v.y); ayh = fmaxf(ayh, v.y);
    azl = fminf(azl, v.z); azh = fmaxf(azh, v.z);
  }
  const float bx0 = bcast63(wave_min_f32(axl)), bx1 = bcast63(wave_max_f32(axh));
  const float by0 = bcast63(wave_min_f32(ayl)), by1 = bcast63(wave_max_f32(ayh));
  const float bz0 = bcast63(wave_min_f32(azl)), bz1 = bcast63(wave_max_f32(azh));

  float cx = xb[0], cy = xb[1], cz = xb[2];  // centroid 0 = point 0
  float dmax = 1e10f;
  double prev_wk = 0.0;  // lane 63's copy is authoritative

  for (int it = 1; it < NPOINT; ++it) {
    // wave-local exact skip test (bit-exact no-op skip, proven r5-r11)
    float ax = fmaxf(fmaxf(bx0 - cx, cx - bx1), 0.f);
    float ay = fmaxf(fmaxf(by0 - cy, cy - by1), 0.f);
    float az = fmaxf(fmaxf(bz0 - cz, cz - bz1), 0.f);
    float LB = ax * ax + ay * ay + az * az;
    int skip = (LB > dmax * 1.00002f) ? 1 : 0;
    skip = __builtin_amdgcn_readfirstlane(skip);
    double wk;
    if (skip) {
      wk = prev_wk;
    } else {
      double key[16];
#pragma unroll
      for (int j = 0; j < 16; ++j) {
        float dx = px[j] - cx, dy = py[j] - cy, dz = pz[j] - cz;
        float dd = dx * dx + dy * dy + dz * dz;  // same expr as rounds 1-11
        float t = fminf(dist[j], dd);
        dist[j] = t;
        key[j] = __longlong_as_double(
            (long long)(((u64)__float_as_uint(t) << 32) | klo[j]));
      }
#pragma unroll
      for (int s = 1; s < 16; s <<= 1) {
#pragma unroll
        for (int j = 0; j < 16; j += 2 * s) key[j] = MAXF64(key[j], key[j + s]);
      }
      wk = wave_max_f64(key[0]);  // lane 63 owns the wave max
      prev_wk = wk;
      dmax = __uint_as_float((u32)__builtin_amdgcn_readlane(
          (int)(u32)(((u64)__double_as_longlong(wk)) >> 32), 63));
    }
    if (lane == 63) kbuf[it & 1][wid] = wk;  // 1 ds_write_b64
    __syncthreads();  // the only barrier per iteration
    // light resolve: 1 ds_read_b64 per lane + 3-step row8 DPP + readlane(7)
    double kv = kbuf[it & 1][lane & 7];
    kv = row8_max_f64(kv);
    u32 rlo = (u32)__builtin_amdgcn_readlane(
        (int)(u32)(u64)__double_as_longlong(kv), 7);
    u32 pos = rlo & 8191u;
    if (tid == 0) cent[b * NPOINT + it] = (int)(8191u - ((rlo >> 13) & 8191u));
    float4 c4 = XYZ4[pos];  // 1 ds_read_b128 broadcast
    cx = c4.x; cy = c4.y; cz = c4.z;
  }
}

// ---------------- Kernel 2: 16-NN per centroid + new_xyz gather (r9 form) ---
// grid NBATCH*NPOINT, block 256. 32 candidate dists per thread in registers.
// Block-wide min-extraction via inverted keys + exact u64 DPP max-reduce.
// (Throughput-bound at 16384 blocks: block-wide form has the lowest
// instruction count per thread — wave-local variant regressed, r11.)
__global__ __launch_bounds__(256) void knn_kernel(const float* __restrict__ xyz,
                                                  const int* __restrict__ cent,
                                                  int* __restrict__ knn,
                                                  float* __restrict__ out_xyz) {
  const int pt = blockIdx.x;       // 0..16383
  const int b = pt >> 11;
  const int tid = threadIdx.x;
  const float* xb = xyz + (size_t)b * NPTS * 3;
  const int ci = cent[pt];
  const float mx = xb[ci * 3 + 0], my = xb[ci * 3 + 1], mz = xb[ci * 3 + 2];
  if (tid < 3) out_xyz[pt * 3 + tid] = xb[ci * 3 + tid];
  const float sm = mx * mx + my * my + mz * mz;

  float d[32];
  float lv = 3.0e38f;
  int lj = 0;
#pragma unroll
  for (int j = 0; j < 32; ++j) {
    int i = tid + 256 * j;
    float x = xb[i * 3 + 0], y = xb[i * 3 + 1], z = xb[i * 3 + 2];
    float dot = mx * x + my * y + mz * z;
    float sp = x * x + y * y + z * z;
    float dd = -2.0f * dot + sm + sp;   // same assoc as reference
    d[j] = dd;
    if (dd < lv) { lv = dd; lj = j; }
  }

  __shared__ __align__(16) u64 kbuf[2][4];
  const int lane = tid & 63;

  for (int p = 0; p < KNN_K; ++p) {
    u32 fb = __float_as_uint(lv);
    u32 mapped = (fb & 0x80000000u) ? ~fb : (fb | 0x80000000u);
    u32 idx = (u32)(tid + (lj << 8));
    u64 ik = ~(((u64)mapped << 32) | (u64)idx);
    u64 wk = wave_max_u64(ik);
    if (lane == 63) kbuf[p & 1][tid >> 6] = wk;
    __syncthreads();
    const ulonglong2* kb = (const ulonglong2*)&kbuf[p & 1][0];
    ulonglong2 q0 = kb[0], q1 = kb[1];
    u64 best = MAXU64(MAXU64(q0.x, q0.y), MAXU64(q1.x, q1.y));
    u32 widx = (u32)(~best);
    if (tid == 0) knn[pt * KNN_K + p] = (int)widx;
    if (tid == (int)(widx & 255u)) {
      int j0 = (int)(widx >> 8);
      float nlv = 3.0e38f;
      int nlj = 0;
#pragma unroll
      for (int j = 0; j < 32; ++j) {
        if (j == j0) d[j] = 3.0e38f;
        if (d[j] < nlv) { nlv = d[j]; nlj = j; }
      }
      lv = nlv; lj = nlj;
    }
  }
}

// ---------------- Kernel 3: gather+GEMM + BN partials + per-(pt,o) max/min ----------------
__global__ __launch_bounds__(256) void gemm_stats_kernel(const float* __restrict__ feat,
                                                         const float* __restrict__ W,
                                                         const int* __restrict__ knn,
                                                         float* __restrict__ part,
                                                         float* __restrict__ mxbuf,
                                                         float* __restrict__ mnbuf) {
  const int tid = threadIdx.x;
  const int o0 = (tid & 63) * 2;
  const int o1 = o0 + 1;
  const int grp = tid >> 6;
  __shared__ __align__(16) float g[128][CIN];
  __shared__ int kidx[128];
  __shared__ float sred[4][128];

  const int rowbase = blockIdx.x * 128;
  if (tid < 128) kidx[tid] = knn[rowbase + tid];

  float4 w0v[16], w1v[16];
  {
    const float4* wv0 = (const float4*)(W + (size_t)o0 * CIN);
    const float4* wv1 = (const float4*)(W + (size_t)o1 * CIN);
#pragma unroll
    for (int q = 0; q < 16; ++q) { w0v[q] = wv0[q]; w1v[q] = wv1[q]; }
  }
  __syncthreads();
#pragma unroll
  for (int s = 0; s < 8; ++s) {
    int v = tid + 256 * s;
    int row = v >> 4, q = v & 15;
    int gr = rowbase + row;
    int bb = gr >> 15;
    const float4* src = (const float4*)(feat + (size_t)(bb * NPTS + kidx[row]) * CIN);
    *((float4*)&g[row][q * 4]) = src[q];
  }
  __syncthreads();

  float s1_0 = 0.f, s2_0 = 0.f, s1_1 = 0.f, s2_1 = 0.f;
#pragma unroll
  for (int pp = 0; pp < 2; ++pp) {
    const int ptl = grp + pp * 4;
    float mx0 = -3.0e38f, mn0 = 3.0e38f, mx1 = -3.0e38f, mn1 = 3.0e38f;
#pragma unroll
    for (int k = 0; k < KNN_K; ++k) {
      const int row = ptl * 16 + k;
      float a0 = 0.f, a1 = 0.f;
#pragma unroll
      for (int q = 0; q < 16; ++q) {
        float4 a = *((const float4*)&g[row][q * 4]);
        a0 += w0v[q].x * a.x + w0v[q].y * a.y + w0v[q].z * a.z + w0v[q].w * a.w;
        a1 += w1v[q].x * a.x + w1v[q].y * a.y + w1v[q].z * a.z + w1v[q].w * a.w;
      }
      s1_0 += a0; s2_0 += a0 * a0; mx0 = fmaxf(mx0, a0); mn0 = fminf(mn0, a0);
      s1_1 += a1; s2_1 += a1 * a1; mx1 = fmaxf(mx1, a1); mn1 = fminf(mn1, a1);
    }
    const size_t pt = (size_t)blockIdx.x * 8 + ptl;
    mxbuf[pt * COUT + o0] = mx0;
    mxbuf[pt * COUT + o1] = mx1;
    mnbuf[pt * COUT + o0] = mn0;
    mnbuf[pt * COUT + o1] = mn1;
  }
  sred[grp][o0] = s1_0; sred[grp][o1] = s1_1;
  __syncthreads();
  if (tid < 128) {
    float t = sred[0][tid] + sred[1][tid] + sred[2][tid] + sred[3][tid];
    part[blockIdx.x * 256 + tid] = t;
  }
  __syncthreads();
  sred[grp][o0] = s2_0; sred[grp][o1] = s2_1;
  __syncthreads();
  if (tid < 128) {
    float t = sred[0][tid] + sred[1][tid] + sred[2][tid] + sred[3][tid];
    part[blockIdx.x * 256 + 128 + tid] = t;
  }
}

// ---------------- Kernel 4: reduce partials -> scale/shift per channel ----------------
__global__ __launch_bounds__(256) void bn_reduce_kernel(const float* __restrict__ part,
                                                        const float* __restrict__ gamma,
                                                        const float* __restrict__ beta,
                                                        float* __restrict__ stats) {
  const int o = blockIdx.x;
  const int tid = threadIdx.x;
  float s1 = 0.f, s2 = 0.f;
  for (int p = tid; p < 2048; p += 256) {
    s1 += part[p * 256 + o];
    s2 += part[p * 256 + 128 + o];
  }
  __shared__ float r1[256], r2[256];
  r1[tid] = s1; r2[tid] = s2;
  __syncthreads();
  for (int s = 128; s >= 1; s >>= 1) {
    if (tid < s) { r1[tid] += r1[tid + s]; r2[tid] += r2[tid + s]; }
    __syncthreads();
  }
  if (tid == 0) {
    const float n = (float)(NBATCH * NPOINT * KNN_K);
    float mean = r1[0] / n;
    float var = r2[0] / n - mean * mean;
    float inv = rsqrtf(var + 1e-5f);
    float sc = gamma[o] * inv;
    stats[o] = sc;
    stats[128 + o] = beta[o] - mean * sc;
  }
}

// ---------------- Kernel 5: finalize out = relu(sel*sc + sh) ----------------
__global__ __launch_bounds__(256) void finalize_kernel(float* __restrict__ out_feat,
                                                       const float* __restrict__ mnbuf,
                                                       const float* __restrict__ stats) {
  const int i = blockIdx.x * 256 + threadIdx.x;
  const int o = i & 127;
  const float sc = stats[o];
  const float sh = stats[128 + o];
  const float mx = out_feat[i];
  const float mn = mnbuf[i];
  const float sel = (sc >= 0.f) ? mx : mn;
  out_feat[i] = fmaxf(sel * sc + sh, 0.f);
}

extern "C" void kernel_launch(void* const* d_in, const int* in_sizes, int n_in,
                              void* d_out, int out_size, void* d_ws, size_t ws_size,
                              hipStream_t stream) {
  const float* xyz = (const float*)d_in[0];
  const float* feat = (const float*)d_in[1];
  const float* W = (const float*)d_in[2];
  const float* gamma = (const float*)d_in[3];
  const float* beta = (const float*)d_in[4];
  float* out = (float*)d_out;

  int* cent = (int*)d_ws;
  int* knn = cent + NBATCH * NPOINT;
  float* part = (float*)(knn + NBATCH * NPOINT * KNN_K);
  float* stats = part + 2048 * 256;
  float* mnbuf = stats + 256;

  float* out_xyz = out;
  float* out_feat = out + NBATCH * NPOINT * 3;

  hipLaunchKernelGGL(fps_kernel, dim3(NBATCH), dim3(512), 0, stream, xyz, cent);
  hipLaunchKernelGGL(knn_kernel, dim3(NBATCH * NPOINT), dim3(256), 0, stream,
                     xyz, cent, knn, out_xyz);
  hipLaunchKernelGGL(gemm_stats_kernel, dim3(2048), dim3(256), 0, stream,
                     feat, W, knn, part, out_feat, mnbuf);
  hipLaunchKernelGGL(bn_reduce_kernel, dim3(128), dim3(256), 0, stream,
                     part, gamma, beta, stats);
  hipLaunchKernelGGL(finalize_kernel, dim3(8192), dim3(256), 0, stream,
                     out_feat, mnbuf, stats);
}